// Round 5
// baseline (4655.014 us; speedup 1.0000x reference)
//
#include <hip/hip_runtime.h>

#define NXg 432
#define NYg 496
#define SCELLS (NXg*NYg)   // 214272
#define PB 6000
#define NPTS 4096
#define DD 64
#define MM 1024
#define KK 4
#define BB 2
#define NROWS (PB*KK)      // 24000
#define NSEG 8
#define SEGPTS (NPTS/NSEG) // 512 points per segment
#define BM 128             // pillars per block
#define BN 64              // points per chunk
#define NCHUNK (SEGPTS/BN) // 8 chunks
#define NPBLK ((PB + BM - 1)/BM)  // 47 pillar blocks
#define SHRINK_TH 0.0025f
#define BN_EPS 1e-3f
#define NEG_INF -3.402823466e38f

// sorted-descending top-4 insert on NAMED scalars; caller guarantees v > v3.
// Within-thread scans are ascending-index, so strict > keeps earliest index on ties.
#define INS4(v, id, v0,v1,v2,v3, i0,i1,i2,i3) { \
    bool g0 = (v) > v0, g1 = (v) > v1, g2 = (v) > v2; \
    v3 = g2 ? v2 : (v);              i3 = g2 ? i2 : (id); \
    v2 = g2 ? (g1 ? v1 : (v)) : v2;  i2 = g2 ? (g1 ? i1 : (id)) : i2; \
    v1 = g1 ? (g0 ? v0 : (v)) : v1;  i1 = g1 ? (g0 ? i0 : (id)) : i1; \
    v0 = g0 ? (v) : v0;              i0 = g0 ? (id) : i0; \
}

// lexicographic (v desc, id asc) insert: order-independent merge of partial
// lists whose index ranges interleave. Matches top_k lowest-index-on-ties.
#define LEXGT(v,id,vk,ik) ((v) > (vk) || ((v) == (vk) && (id) < (ik)))
#define INS4L(v, id, v0,v1,v2,v3, i0,i1,i2,i3) { \
    if (LEXGT(v,id,v3,i3)) { \
        bool g0 = LEXGT(v,id,v0,i0), g1 = LEXGT(v,id,v1,i1), g2 = LEXGT(v,id,v2,i2); \
        v3 = g2 ? v2 : (v);              i3 = g2 ? i2 : (id); \
        v2 = g2 ? (g1 ? v1 : (v)) : v2;  i2 = g2 ? (g1 ? i1 : (id)) : i2; \
        v1 = g1 ? (g0 ? v0 : (v)) : v1;  i1 = g1 ? (g0 ? i0 : (id)) : i1; \
        v0 = g0 ? (v) : v0;              i0 = g0 ? (id) : i0; \
    } \
}

// ---------------- inverse map ----------------
__global__ __launch_bounds__(256) void k_init_inv(int* __restrict__ inv) {
    int i = blockIdx.x*256 + threadIdx.x;
    inv[i] = -1;
}

__global__ __launch_bounds__(256) void k_scatter_inv(const int* __restrict__ coords,
                                                     int* __restrict__ inv) {
    int i = blockIdx.x*256 + threadIdx.x;
    if (i >= BB*PB) return;
    int b = i / PB, p = i % PB;
    const int* c = coords + (size_t)i*3;
    int flat = c[0] + c[1]*NXg + c[2];
    inv[b*SCELLS + flat] = p;
}

// ---------------- score + top-4: tiled GEMM, top-k in registers ----------------
// Round-4 post-mortem: FETCH 7.8GB / WRITE 4.4GB per dispatch = SCRATCH SPILL.
// VGPR=84 ~= 512/6: launch_bounds(256,3) only floors occupancy; the allocator
// targeted 6 waves/SIMD (85-reg tier) -- impossible anyway with 48KB LDS
// (3 blocks/CU max) -- and spilled ~40 regs, reloaded every k-step.
// Fix: (a) amdgpu_waves_per_eu(3,3) pins the target at the LDS-limited
// occupancy -> VGPR cap ~170; (b) B operand loaded one float4 per j inside
// the loop: live set = acc 32 + aR 16 + bj 4 + topk 32 + addr ~15 = ~99 regs.
// LDS reads stay 8-way same-address broadcasts (free) and bank-conflict-free:
// A stored col^=(row>>2)&15 (read k4^(rg&15)), B col^=(row>>3) (read k4^cg).
// Cycle model @3 blocks/CU: 16384 FMA-inst x 2cyc x 3 waves/SIMD ~ 41 us VALU.
__global__ __launch_bounds__(256)
__attribute__((amdgpu_waves_per_eu(3,3)))
void k_score_topk(const float* __restrict__ pillars,
                  const float* __restrict__ points,
                  float* __restrict__ pV,
                  int* __restrict__ pI) {
    __shared__ __align__(16) char smem[49152];
    float4* sA4 = (float4*)smem;          // [128][16] f4, col^=(row>>2)&15
    float4* sB4 = sA4 + 128*16;           // [64][16] f4,  col^=(row>>3)

    const int b = blockIdx.y;
    const int seg = blockIdx.z;
    const int t = threadIdx.x;
    const int p0 = blockIdx.x * BM;
    const int j0 = seg * SEGPTS;
    const int rg = t >> 3;                // 32 row groups (4 pillars each)
    const int cg = t & 7;                 // 8 col groups (8 points each)

    const float4* pil4  = (const float4*)pillars;
    const float4* ptsB4 = (const float4*)(points + (size_t)b*NPTS*DD);

    // ---- stage A once (rows clamped for the 6000..6015 pad) ----
    #pragma unroll
    for (int q = 0; q < 8; q++) {
        int g = q*256 + t;
        int p = g >> 4, c4 = g & 15;
        int gp = p0 + p; if (gp > PB-1) gp = PB-1;
        sA4[p*16 + (c4 ^ ((p >> 2) & 15))] = pil4[((size_t)b*PB + gp)*16 + c4];
    }
    // ---- stage B chunk 0 ----
    {
        const float4* src = ptsB4 + (size_t)j0*16;
        #pragma unroll
        for (int q = 0; q < 4; q++) {
            int g = q*256 + t;
            int pt = g >> 4, c4 = g & 15;
            sB4[pt*16 + (c4 ^ (pt >> 3))] = src[g];
        }
    }

    // per-thread top-4 lists, one per owned pillar row (static indices only)
    float tv0[4], tv1[4], tv2[4], tv3[4];
    int   ti0[4], ti1[4], ti2[4], ti3[4];
    #pragma unroll
    for (int i = 0; i < 4; i++) {
        tv0[i]=NEG_INF; tv1[i]=NEG_INF; tv2[i]=NEG_INF; tv3[i]=NEG_INF;
        ti0[i]=0; ti1[i]=0; ti2[i]=0; ti3[i]=0;
    }

    __syncthreads();

    for (int c = 0; c < NCHUNK; c++) {
        // ---- GEMM: 4 pillars x 8 points x 64 k per thread ----
        float acc[4][8];
        #pragma unroll
        for (int i = 0; i < 4; i++)
            #pragma unroll
            for (int j = 0; j < 8; j++) acc[i][j] = 0.f;

        #pragma unroll
        for (int k4 = 0; k4 < 16; k4++) {
            float4 aR[4];
            #pragma unroll
            for (int i = 0; i < 4; i++)
                aR[i] = sA4[(rg*4+i)*16 + (k4 ^ (rg & 15))];
            #pragma unroll
            for (int j = 0; j < 8; j++) {
                float4 bj = sB4[(cg*8+j)*16 + (k4 ^ cg)];
                #pragma unroll
                for (int i = 0; i < 4; i++)
                    acc[i][j] += aR[i].x*bj.x + aR[i].y*bj.y
                               + aR[i].z*bj.z + aR[i].w*bj.w;
            }
        }

        // ---- fold into register top-4 (ascending j; ascending c across chunks) ----
        int jb = j0 + c*BN + cg*8;
        #pragma unroll
        for (int i = 0; i < 4; i++)
            #pragma unroll
            for (int j = 0; j < 8; j++) {
                float v = acc[i][j];
                if (v > tv3[i]) INS4(v, jb+j, tv0[i],tv1[i],tv2[i],tv3[i],
                                               ti0[i],ti1[i],ti2[i],ti3[i])
            }

        __syncthreads();   // all reads of B(c) done
        if (c+1 < NCHUNK) {
            const float4* src = ptsB4 + (size_t)(j0 + (c+1)*BN)*16;
            #pragma unroll
            for (int q = 0; q < 4; q++) {
                int g = q*256 + t;
                int pt = g >> 4, c4 = g & 15;
                sB4[pt*16 + (c4 ^ (pt >> 3))] = src[g];
            }
        }
        __syncthreads();   // B(c+1) visible
    }

    // ---- merge 8 cg-partials per pillar (lexicographic, order-independent) ----
    float* vS = (float*)smem;             // [8][128][4] values  (16 KB, A region)
    int*   iS = (int*)(smem + 32768);     // [8][128][4] indices (16 KB, B region)
    #pragma unroll
    for (int i = 0; i < 4; i++) {
        int base = (cg*BM + rg*4 + i)*4;
        vS[base+0]=tv0[i]; vS[base+1]=tv1[i]; vS[base+2]=tv2[i]; vS[base+3]=tv3[i];
        iS[base+0]=ti0[i]; iS[base+1]=ti1[i]; iS[base+2]=ti2[i]; iS[base+3]=ti3[i];
    }
    __syncthreads();
    if (t < BM) {
        float fv0=NEG_INF, fv1=NEG_INF, fv2=NEG_INF, fv3=NEG_INF;
        int fi0=0, fi1=0, fi2=0, fi3=0;
        #pragma unroll
        for (int s = 0; s < 8; s++) {
            int base = (s*BM + t)*4;
            #pragma unroll
            for (int q = 0; q < 4; q++) {
                float v = vS[base+q];
                int id = iS[base+q];
                INS4L(v, id, fv0,fv1,fv2,fv3, fi0,fi1,fi2,fi3)
            }
        }
        if (p0 + t < PB) {
            size_t ob = (((size_t)b*NSEG + seg)*PB + (p0 + t))*KK;
            pV[ob+0]=fv0; pV[ob+1]=fv1; pV[ob+2]=fv2; pV[ob+3]=fv3;
            pI[ob+0]=fi0; pI[ob+1]=fi1; pI[ob+2]=fi2; pI[ob+3]=fi3;
        }
    }
}

// ---------------- merge NSEG partial top-4 lists ----------------
__global__ __launch_bounds__(256) void k_merge(const float* __restrict__ pV,
                                               const int* __restrict__ pI,
                                               int* __restrict__ idxOut) {
    int i = blockIdx.x*256 + threadIdx.x;
    if (i >= BB*PB) return;
    int b = i / PB, p = i % PB;
    float fv0=NEG_INF, fv1=NEG_INF, fv2=NEG_INF, fv3=NEG_INF;
    int fi0=0, fi1=0, fi2=0, fi3=0;
    for (int s = 0; s < NSEG; s++) {   // ascending seg = ascending point ranges
        size_t base = (((size_t)b*NSEG + s)*PB + p)*KK;
        #pragma unroll
        for (int q = 0; q < 4; q++) {
            float v = pV[base+q];
            if (v > fv3) INS4(v, pI[base+q], fv0,fv1,fv2,fv3, fi0,fi1,fi2,fi3)
        }
    }
    idxOut[(size_t)i*KK+0]=fi0; idxOut[(size_t)i*KK+1]=fi1;
    idxOut[(size_t)i*KK+2]=fi2; idxOut[(size_t)i*KK+3]=fi3;
}

// ---------------- logits GEMM: X[24000x64] @ memw^T[64x1024] ----------------
__global__ __launch_bounds__(256) void k_logits(const float* __restrict__ points,
                                                const int* __restrict__ idxIn,
                                                const float* __restrict__ memw,
                                                float* __restrict__ logits,
                                                int b) {
    __shared__ float4 sX4[64*16];
    __shared__ int sId[64];
    const int t = threadIdx.x;
    const int lane = t & 63, wv = t >> 6;
    const int row0 = blockIdx.x * 64;
    const int cg = blockIdx.y * 256 + wv * 64;

    if (t < 64) sId[t] = idxIn[(size_t)b*NROWS + row0 + t];

    const float4* mw4 = (const float4*)memw;
    float4 wreg[16];
    #pragma unroll
    for (int d4 = 0; d4 < 16; d4++) wreg[d4] = mw4[(size_t)(cg + lane)*16 + d4];

    __syncthreads();
    const float4* ptsB4 = (const float4*)(points + (size_t)b*NPTS*DD);
    for (int i = t; i < 1024; i += 256) {
        int r = i >> 4, c = i & 15;
        sX4[i] = ptsB4[(size_t)sId[r]*16 + c];
    }
    __syncthreads();

    for (int r = 0; r < 64; r += 2) {
        float a0 = 0.f, a1 = 0.f;
        #pragma unroll
        for (int d4 = 0; d4 < 16; d4++) {
            float4 x0 = sX4[r*16 + d4];
            float4 x1 = sX4[(r+1)*16 + d4];
            a0 += wreg[d4].x*x0.x + wreg[d4].y*x0.y + wreg[d4].z*x0.z + wreg[d4].w*x0.w;
            a1 += wreg[d4].x*x1.x + wreg[d4].y*x1.y + wreg[d4].z*x1.z + wreg[d4].w*x1.w;
        }
        logits[(size_t)(row0 + r)*MM + cg + lane] = a0;
        logits[(size_t)(row0 + r + 1)*MM + cg + lane] = a1;
    }
}

// ---------------- mem-unit: stats + att-on-the-fly GEMM + adapt ----------------
__global__ __launch_bounds__(256) void k_mo(const float* __restrict__ logits,
                                            const float* __restrict__ memw,
                                            const float* __restrict__ adaptw,
                                            float* __restrict__ hOut,
                                            int b) {
    __shared__ __align__(16) char smem[77824];
    float4* sAtt4 = (float4*)smem;              // [48][16] f4
    float4* sW4   = (float4*)(smem + 12288);    // [64 m][16 c4]
    float*  sWf   = (float*)sW4;
    __shared__ float sM[48], sRinv[48], sRsc[48];
    const int t = threadIdx.x;
    const int lane = t & 63, wv = t >> 6;
    const int p0 = blockIdx.x * 12;
    const int row0 = p0 * 4;

    const float4* lg4 = (const float4*)logits;
    #pragma unroll
    for (int rr = 0; rr < 12; rr++) {
        int r = wv*12 + rr;
        size_t base = (size_t)(row0 + r)*256;
        float4 l0 = lg4[base + lane];
        float4 l1 = lg4[base + 64 + lane];
        float4 l2 = lg4[base + 128 + lane];
        float4 l3 = lg4[base + 192 + lane];
        float m = fmaxf(fmaxf(fmaxf(l0.x,l0.y),fmaxf(l0.z,l0.w)),
                 fmaxf(fmaxf(fmaxf(l1.x,l1.y),fmaxf(l1.z,l1.w)),
                 fmaxf(fmaxf(fmaxf(l2.x,l2.y),fmaxf(l2.z,l2.w)),
                       fmaxf(fmaxf(l3.x,l3.y),fmaxf(l3.z,l3.w)))));
        #pragma unroll
        for (int off = 1; off < 64; off <<= 1) m = fmaxf(m, __shfl_xor(m, off));
        l0.x=__expf(l0.x-m); l0.y=__expf(l0.y-m); l0.z=__expf(l0.z-m); l0.w=__expf(l0.w-m);
        l1.x=__expf(l1.x-m); l1.y=__expf(l1.y-m); l1.z=__expf(l1.z-m); l1.w=__expf(l1.w-m);
        l2.x=__expf(l2.x-m); l2.y=__expf(l2.y-m); l2.z=__expf(l2.z-m); l2.w=__expf(l2.w-m);
        l3.x=__expf(l3.x-m); l3.y=__expf(l3.y-m); l3.z=__expf(l3.z-m); l3.w=__expf(l3.w-m);
        float s = (l0.x+l0.y+l0.z+l0.w) + (l1.x+l1.y+l1.z+l1.w)
                + (l2.x+l2.y+l2.z+l2.w) + (l3.x+l3.y+l3.z+l3.w);
        #pragma unroll
        for (int off = 1; off < 64; off <<= 1) s += __shfl_xor(s, off);
        float rinv = 1.f / s;
        float sh = 0.f;
        {
            float e, tt;
            e=l0.x*rinv; tt=e-SHRINK_TH; sh += tt>0.f ? e*tt/(tt+1e-12f) : 0.f;
            e=l0.y*rinv; tt=e-SHRINK_TH; sh += tt>0.f ? e*tt/(tt+1e-12f) : 0.f;
            e=l0.z*rinv; tt=e-SHRINK_TH; sh += tt>0.f ? e*tt/(tt+1e-12f) : 0.f;
            e=l0.w*rinv; tt=e-SHRINK_TH; sh += tt>0.f ? e*tt/(tt+1e-12f) : 0.f;
            e=l1.x*rinv; tt=e-SHRINK_TH; sh += tt>0.f ? e*tt/(tt+1e-12f) : 0.f;
            e=l1.y*rinv; tt=e-SHRINK_TH; sh += tt>0.f ? e*tt/(tt+1e-12f) : 0.f;
            e=l1.z*rinv; tt=e-SHRINK_TH; sh += tt>0.f ? e*tt/(tt+1e-12f) : 0.f;
            e=l1.w*rinv; tt=e-SHRINK_TH; sh += tt>0.f ? e*tt/(tt+1e-12f) : 0.f;
            e=l2.x*rinv; tt=e-SHRINK_TH; sh += tt>0.f ? e*tt/(tt+1e-12f) : 0.f;
            e=l2.y*rinv; tt=e-SHRINK_TH; sh += tt>0.f ? e*tt/(tt+1e-12f) : 0.f;
            e=l2.z*rinv; tt=e-SHRINK_TH; sh += tt>0.f ? e*tt/(tt+1e-12f) : 0.f;
            e=l2.w*rinv; tt=e-SHRINK_TH; sh += tt>0.f ? e*tt/(tt+1e-12f) : 0.f;
            e=l3.x*rinv; tt=e-SHRINK_TH; sh += tt>0.f ? e*tt/(tt+1e-12f) : 0.f;
            e=l3.y*rinv; tt=e-SHRINK_TH; sh += tt>0.f ? e*tt/(tt+1e-12f) : 0.f;
            e=l3.z*rinv; tt=e-SHRINK_TH; sh += tt>0.f ? e*tt/(tt+1e-12f) : 0.f;
            e=l3.w*rinv; tt=e-SHRINK_TH; sh += tt>0.f ? e*tt/(tt+1e-12f) : 0.f;
        }
        #pragma unroll
        for (int off = 1; off < 64; off <<= 1) sh += __shfl_xor(sh, off);
        if (lane == 0) { sM[r] = m; sRinv[r] = rinv; sRsc[r] = 1.f/(sh + 1e-12f); }
    }
    __syncthreads();

    float acc[12];
    #pragma unroll
    for (int s=0;s<12;s++) acc[s]=0.f;
    const float4* mw4 = (const float4*)memw;

    for (int tile = 0; tile < 16; tile++) {
        __syncthreads();
        for (int i = t; i < 768; i += 256) {
            int rr = i >> 4, m4 = i & 15;
            float4 lg = lg4[(size_t)(row0 + rr)*256 + tile*16 + m4];
            float m = sM[rr], rinv = sRinv[rr], rsc = sRsc[rr];
            float4 o;
            float e, tt;
            e=__expf(lg.x-m)*rinv; tt=e-SHRINK_TH; o.x = (tt>0.f ? e*tt/(tt+1e-12f) : 0.f)*rsc;
            e=__expf(lg.y-m)*rinv; tt=e-SHRINK_TH; o.y = (tt>0.f ? e*tt/(tt+1e-12f) : 0.f)*rsc;
            e=__expf(lg.z-m)*rinv; tt=e-SHRINK_TH; o.z = (tt>0.f ? e*tt/(tt+1e-12f) : 0.f)*rsc;
            e=__expf(lg.w-m)*rinv; tt=e-SHRINK_TH; o.w = (tt>0.f ? e*tt/(tt+1e-12f) : 0.f)*rsc;
            sAtt4[rr*16 + m4] = o;
        }
        #pragma unroll 4
        for (int i = t; i < 1024; i += 256) {
            int m = i >> 4, c4 = i & 15;
            sW4[m*16 + c4] = mw4[(size_t)(tile*64 + m)*16 + c4];
        }
        __syncthreads();
        #pragma unroll 4
        for (int m4 = 0; m4 < 16; m4++) {
            float w0 = sWf[(m4*4+0)*64 + lane];
            float w1 = sWf[(m4*4+1)*64 + lane];
            float w2 = sWf[(m4*4+2)*64 + lane];
            float w3 = sWf[(m4*4+3)*64 + lane];
            #pragma unroll
            for (int s = 0; s < 12; s++) {
                float4 a4 = sAtt4[(wv + 4*s)*16 + m4];
                acc[s] += a4.x*w0 + a4.y*w1 + a4.z*w2 + a4.w*w3;
            }
        }
    }
    __syncthreads();
    float* sMo = (float*)smem;
    float4* sA4 = (float4*)(smem + 12288);
    #pragma unroll
    for (int s = 0; s < 12; s++) {
        int r = wv + 4*s;
        sMo[r*64 + lane] = acc[s];
    }
    const float4* adG4 = (const float4*)adaptw;
    for (int i = t; i < 4096; i += 256) {
        int c = i >> 6, j4 = i & 63;
        sA4[c*64 + (j4 ^ (c & 15))] = adG4[c*64 + j4];
    }
    __syncthreads();
    const float4* sMo4 = (const float4*)sMo;
    float h0=0.f, h1=0.f, h2=0.f;
    #pragma unroll 8
    for (int j4 = 0; j4 < 64; j4++) {
        float4 a4 = sA4[lane*64 + (j4 ^ (lane & 15))];
        int sub = (j4 >> 4)*16 + (j4 & 15);
        float4 q0 = sMo4[(4*(wv+0))*16 + sub];
        float4 q1 = sMo4[(4*(wv+4))*16 + sub];
        float4 q2 = sMo4[(4*(wv+8))*16 + sub];
        h0 += q0.x*a4.x + q0.y*a4.y + q0.z*a4.z + q0.w*a4.w;
        h1 += q1.x*a4.x + q1.y*a4.y + q1.z*a4.z + q1.w*a4.w;
        h2 += q2.x*a4.x + q2.y*a4.y + q2.z*a4.z + q2.w*a4.w;
    }
    hOut[((size_t)b*PB + p0 + wv + 0)*DD + lane] = h0;
    hOut[((size_t)b*PB + p0 + wv + 4)*DD + lane] = h1;
    hOut[((size_t)b*PB + p0 + wv + 8)*DD + lane] = h2;
}

// ---------------- batchnorm stats, two-stage ----------------
__global__ __launch_bounds__(256) void k_bn1(const float* __restrict__ h,
                                             float* __restrict__ pSum,
                                             float* __restrict__ pSq) {
    const int bid = blockIdx.x;
    const int b = bid >> 5, ch = bid & 31;
    const int r0 = ch*188;
    int r1 = r0 + 188; if (r1 > PB) r1 = PB;
    __shared__ float sS[4*64], sS2[4*64];
    const int t = threadIdx.x;
    const int c = t & 63, stripe = t >> 6;
    float s = 0.f, s2 = 0.f;
    for (int r = r0 + stripe; r < r1; r += 4) {
        float v = h[((size_t)b*PB + r)*DD + c];
        s += v; s2 += v*v;
    }
    sS[stripe*64 + c] = s; sS2[stripe*64 + c] = s2;
    __syncthreads();
    if (t < 64) {
        float ts = sS[t] + sS[64+t] + sS[128+t] + sS[192+t];
        float ts2 = sS2[t] + sS2[64+t] + sS2[128+t] + sS2[192+t];
        pSum[(size_t)bid*64 + t] = ts;
        pSq[(size_t)bid*64 + t] = ts2;
    }
}

__global__ __launch_bounds__(64) void k_bn2(const float* __restrict__ pSum,
                                            const float* __restrict__ pSq,
                                            const float* __restrict__ gamma,
                                            float* __restrict__ bnMu,
                                            float* __restrict__ bnScale) {
    const int b = blockIdx.x;
    const int t = threadIdx.x;
    float ts = 0.f, ts2 = 0.f;
    for (int ch = 0; ch < 32; ch++) {
        ts += pSum[(size_t)(b*32 + ch)*64 + t];
        ts2 += pSq[(size_t)(b*32 + ch)*64 + t];
    }
    float mu = ts / (float)PB;
    float var = ts2 / (float)PB - mu*mu;
    if (var < 0.f) var = 0.f;
    bnMu[b*64+t] = mu;
    bnScale[b*64+t] = gamma[t] / sqrtf(var + BN_EPS);
}

// ---------------- dense fill (gather) ----------------
__global__ __launch_bounds__(256) void k_fill(const int* __restrict__ inv,
                                              const float* __restrict__ pillars,
                                              const float* __restrict__ h,
                                              const float* __restrict__ bnMu,
                                              const float* __restrict__ bnScale,
                                              const float* __restrict__ beta,
                                              float* __restrict__ out) {
    const int b = blockIdx.y;
    const int f = blockIdx.x*256 + threadIdx.x;
    __shared__ float sMu[64], sSc[64], sBe[64];
    if (threadIdx.x < 64) {
        sMu[threadIdx.x] = bnMu[b*64+threadIdx.x];
        sSc[threadIdx.x] = bnScale[b*64+threadIdx.x];
        sBe[threadIdx.x] = beta[threadIdx.x];
    }
    __syncthreads();
    int iv = inv[b*SCELLS + f];
    bool occ = iv >= 0;
    int iv0 = occ ? iv : 0;
    float* sp = out + (size_t)b*128*SCELLS;
    const float* prow = pillars + ((size_t)b*PB + iv0)*DD;
    const float* hrow = h + ((size_t)b*PB + iv0)*DD;
    #pragma unroll 4
    for (int c = 0; c < 64; c++)
        sp[(size_t)c*SCELLS + f] = occ ? prow[c] : 0.f;
    #pragma unroll 4
    for (int c = 0; c < 64; c++) {
        float v = 0.f;
        if (occ) {
            float hv = hrow[c];
            v = fmaxf((hv - sMu[c])*sSc[c] + sBe[c], 0.f);
        }
        sp[(size_t)(64+c)*SCELLS + f] = v;
    }
    float* pi = out + (size_t)BB*128*SCELLS + (size_t)b*3*SCELLS;
    pi[f]              = occ ? (float)(f / NXg) : 0.f;
    pi[SCELLS + f]     = occ ? (float)(f % NXg) : 0.f;
    pi[2*(size_t)SCELLS + f] = 0.f;
}

extern "C" void kernel_launch(void* const* d_in, const int* in_sizes, int n_in,
                              void* d_out, int out_size, void* d_ws, size_t ws_size,
                              hipStream_t stream) {
    const float* pillars = (const float*)d_in[0];
    const float* points  = (const float*)d_in[1];
    const int*   coords  = (const int*)d_in[2];
    const float* adaptw  = (const float*)d_in[3];
    const float* memw    = (const float*)d_in[4];
    const float* gamma   = (const float*)d_in[5];
    const float* beta    = (const float*)d_in[6];
    float* out = (float*)d_out;

    char* w = (char*)d_ws;
    int* inv = (int*)w;        w += (size_t)BB*SCELLS*4;
    int* idx = (int*)w;        w += (size_t)BB*PB*KK*4;
    float* h = (float*)w;      w += (size_t)BB*PB*DD*4;
    float* bnMu = (float*)w;   w += (size_t)BB*64*4;
    float* bnScale = (float*)w; w += (size_t)BB*64*4;
    float* pSum = (float*)w;   w += (size_t)BB*32*64*4;
    float* pSq = (float*)w;    w += (size_t)BB*32*64*4;
    float* logits = (float*)w;                    // 98.3 MB, per-batch reuse
    // pV/pI alias logits: score+merge fully complete (stream-ordered) before
    // k_logits writes this region. 2*8*6000*4*4B*2 = 3.1 MB << 98.3 MB.
    float* pV = logits;
    int*   pI = (int*)(logits + (size_t)BB*NSEG*PB*KK);

    k_init_inv<<<dim3(BB*SCELLS/256), dim3(256), 0, stream>>>(inv);
    k_scatter_inv<<<dim3((BB*PB+255)/256), dim3(256), 0, stream>>>(coords, inv);
    k_score_topk<<<dim3(NPBLK, BB, NSEG), dim3(256), 0, stream>>>(pillars, points, pV, pI);
    k_merge<<<dim3((BB*PB+255)/256), dim3(256), 0, stream>>>(pV, pI, idx);
    for (int b = 0; b < BB; b++) {
        k_logits<<<dim3(NROWS/64, 4), dim3(256), 0, stream>>>(points, idx, memw, logits, b);
        k_mo<<<dim3(PB/12), dim3(256), 0, stream>>>(logits, memw, adaptw, h, b);
    }
    k_bn1<<<dim3(BB*32), dim3(256), 0, stream>>>(h, pSum, pSq);
    k_bn2<<<dim3(BB), dim3(64), 0, stream>>>(pSum, pSq, gamma, bnMu, bnScale);
    k_fill<<<dim3(SCELLS/256, BB), dim3(256), 0, stream>>>(inv, pillars, h, bnMu, bnScale, beta, out);
}

// Round 6
// 3201.871 us; speedup vs baseline: 1.4538x; 1.4538x over previous
//
#include <hip/hip_runtime.h>

#define NXg 432
#define NYg 496
#define SCELLS (NXg*NYg)   // 214272
#define PB 6000
#define NPTS 4096
#define DD 64
#define MM 1024
#define KK 4
#define BB 2
#define NROWS (PB*KK)      // 24000
#define BM 128             // pillars per block
#define BNCH 64            // points per LDS chunk
#define NCHB 4             // chunks per block -> 256 points/block
#define NYBLK (NPTS/(BNCH*NCHB))  // 16
#define NPBLK ((PB + BM - 1)/BM)  // 47 pillar blocks
#define SHRINK_TH 0.0025f
#define BN_EPS 1e-3f
#define NEG_INF -3.402823466e38f

// sorted-descending top-4 insert on NAMED scalars; caller guarantees v > v3.
// Within-lane scans are ascending-index, so strict > keeps earliest index on ties.
#define INS4(v, id, v0,v1,v2,v3, i0,i1,i2,i3) { \
    bool g0 = (v) > v0, g1 = (v) > v1, g2 = (v) > v2; \
    v3 = g2 ? v2 : (v);              i3 = g2 ? i2 : (id); \
    v2 = g2 ? (g1 ? v1 : (v)) : v2;  i2 = g2 ? (g1 ? i1 : (id)) : i2; \
    v1 = g1 ? (g0 ? v0 : (v)) : v1;  i1 = g1 ? (g0 ? i0 : (id)) : i1; \
    v0 = g0 ? (v) : v0;              i0 = g0 ? (id) : i0; \
}

// lexicographic (v desc, id asc) insert: order-independent merge of partial
// lists from different lanes. Matches stable top_k lowest-index-on-ties.
#define LEXGT(v,id,vk,ik) ((v) > (vk) || ((v) == (vk) && (id) < (ik)))
#define INS4L(v, id, v0,v1,v2,v3, i0,i1,i2,i3) { \
    if (LEXGT(v,id,v3,i3)) { \
        bool g0 = LEXGT(v,id,v0,i0), g1 = LEXGT(v,id,v1,i1), g2 = LEXGT(v,id,v2,i2); \
        v3 = g2 ? v2 : (v);              i3 = g2 ? i2 : (id); \
        v2 = g2 ? (g1 ? v1 : (v)) : v2;  i2 = g2 ? (g1 ? i1 : (id)) : i2; \
        v1 = g1 ? (g0 ? v0 : (v)) : v1;  i1 = g1 ? (g0 ? i0 : (id)) : i1; \
        v0 = g0 ? (v) : v0;              i0 = g0 ? (id) : i0; \
    } \
}

// ---------------- inverse map ----------------
__global__ __launch_bounds__(256) void k_init_inv(int* __restrict__ inv) {
    int i = blockIdx.x*256 + threadIdx.x;
    inv[i] = -1;
}

__global__ __launch_bounds__(256) void k_scatter_inv(const int* __restrict__ coords,
                                                     int* __restrict__ inv) {
    int i = blockIdx.x*256 + threadIdx.x;
    if (i >= BB*PB) return;
    int b = i / PB, p = i % PB;
    const int* c = coords + (size_t)i*3;
    int flat = c[0] + c[1]*NXg + c[2];
    inv[b*SCELLS + flat] = p;
}

// ---------------- score GEMM: scores -> global (no top-k state) ----------------
// Round-5 post-mortem: top-k register state (~32 regs live across the whole
// chunk loop) is what pushed peak pressure past the allocator's stubborn ~84
// budget (two occupancy hints ignored; acc spilled -> 12 GB scratch traffic).
// Fix: remove it. Pure GEMM writes the 98.3MB score matrix (== logits region
// size exactly) to global; a separate streaming kernel does the top-4.
// Peak live here: acc 32 + aR 16 + bj 4 + addr ~15 = ~70 regs -> no spill.
// Same conflict-free XOR swizzles as r4/r5 (verified clean in PMC).
__global__ __launch_bounds__(256) void k_score(const float* __restrict__ pillars,
                                               const float* __restrict__ points,
                                               float* __restrict__ scores,
                                               int b) {
    __shared__ __align__(16) char smem[49152];
    float4* sA4 = (float4*)smem;          // [128][16] f4, col^=(row>>2)&15
    float4* sB4 = sA4 + 128*16;           // [64][16] f4,  col^=(row>>3)

    const int t = threadIdx.x;
    const int p0 = blockIdx.x * BM;
    const int j0 = blockIdx.y * (BNCH*NCHB);
    const int rg = t >> 3;                // 32 row groups (4 pillars each)
    const int cg = t & 7;                 // 8 col groups (8 points each)

    const float4* pil4  = (const float4*)pillars;
    const float4* ptsB4 = (const float4*)(points + (size_t)b*NPTS*DD);

    // ---- stage A once (rows clamped for the 6000..6015 pad) ----
    #pragma unroll
    for (int q = 0; q < 8; q++) {
        int g = q*256 + t;
        int p = g >> 4, c4 = g & 15;
        int gp = p0 + p; if (gp > PB-1) gp = PB-1;
        sA4[p*16 + (c4 ^ ((p >> 2) & 15))] = pil4[((size_t)b*PB + gp)*16 + c4];
    }
    // ---- stage B chunk 0 ----
    {
        const float4* src = ptsB4 + (size_t)j0*16;
        #pragma unroll
        for (int q = 0; q < 4; q++) {
            int g = q*256 + t;
            int pt = g >> 4, c4 = g & 15;
            sB4[pt*16 + (c4 ^ (pt >> 3))] = src[g];
        }
    }
    __syncthreads();

    for (int c = 0; c < NCHB; c++) {
        // ---- GEMM: 4 pillars x 8 points x 64 k per thread ----
        float acc[4][8];
        #pragma unroll
        for (int i = 0; i < 4; i++)
            #pragma unroll
            for (int j = 0; j < 8; j++) acc[i][j] = 0.f;

        #pragma unroll
        for (int k4 = 0; k4 < 16; k4++) {
            float4 aR[4];
            #pragma unroll
            for (int i = 0; i < 4; i++)
                aR[i] = sA4[(rg*4+i)*16 + (k4 ^ (rg & 15))];
            #pragma unroll
            for (int j = 0; j < 8; j++) {
                float4 bj = sB4[(cg*8+j)*16 + (k4 ^ cg)];
                #pragma unroll
                for (int i = 0; i < 4; i++)
                    acc[i][j] += aR[i].x*bj.x + aR[i].y*bj.y
                               + aR[i].z*bj.z + aR[i].w*bj.w;
            }
        }
        __syncthreads();   // all reads of B(c) done
        if (c+1 < NCHB) {
            const float4* src = ptsB4 + (size_t)(j0 + (c+1)*BNCH)*16;
            #pragma unroll
            for (int q = 0; q < 4; q++) {
                int g = q*256 + t;
                int pt = g >> 4, c4 = g & 15;
                sB4[pt*16 + (c4 ^ (pt >> 3))] = src[g];
            }
        }
        // ---- stream scores to global (overlaps the staging loads) ----
        int jb = j0 + c*BNCH + cg*8;
        #pragma unroll
        for (int i = 0; i < 4; i++) {
            int gp = p0 + rg*4 + i;
            if (gp < PB) {
                float4* dst = (float4*)(scores + (size_t)gp*NPTS + jb);
                dst[0] = make_float4(acc[i][0], acc[i][1], acc[i][2], acc[i][3]);
                dst[1] = make_float4(acc[i][4], acc[i][5], acc[i][6], acc[i][7]);
            }
        }
        __syncthreads();   // B(c+1) visible
    }
}

// ---------------- top-4 scan: one wave per pillar row ----------------
// Lane l takes float4s at s*64+l (256B-coalesced per step; lane-ascending
// indices -> strict-> INS4 keeps earliest index). Then 6-stage shfl_xor
// butterfly with lexicographic INS4L -> global top-4 in all lanes.
__global__ __launch_bounds__(256) void k_scan(const float* __restrict__ scores,
                                              int* __restrict__ idxOut,
                                              int b) {
    const int wv = threadIdx.x >> 6, lane = threadIdx.x & 63;
    const int p = blockIdx.x*4 + wv;
    const float4* row = (const float4*)(scores + (size_t)p*NPTS);

    float tv0=NEG_INF, tv1=NEG_INF, tv2=NEG_INF, tv3=NEG_INF;
    int   ti0=0, ti1=0, ti2=0, ti3=0;

    #pragma unroll
    for (int s = 0; s < 16; s++) {
        float4 v = row[s*64 + lane];
        int j = (s*64 + lane)*4;
        if (v.x > tv3) INS4(v.x, j+0, tv0,tv1,tv2,tv3, ti0,ti1,ti2,ti3)
        if (v.y > tv3) INS4(v.y, j+1, tv0,tv1,tv2,tv3, ti0,ti1,ti2,ti3)
        if (v.z > tv3) INS4(v.z, j+2, tv0,tv1,tv2,tv3, ti0,ti1,ti2,ti3)
        if (v.w > tv3) INS4(v.w, j+3, tv0,tv1,tv2,tv3, ti0,ti1,ti2,ti3)
    }

    #pragma unroll
    for (int off = 1; off < 64; off <<= 1) {
        float ov0 = __shfl_xor(tv0, off), ov1 = __shfl_xor(tv1, off);
        float ov2 = __shfl_xor(tv2, off), ov3 = __shfl_xor(tv3, off);
        int   oi0 = __shfl_xor(ti0, off), oi1 = __shfl_xor(ti1, off);
        int   oi2 = __shfl_xor(ti2, off), oi3 = __shfl_xor(ti3, off);
        INS4L(ov0, oi0, tv0,tv1,tv2,tv3, ti0,ti1,ti2,ti3)
        INS4L(ov1, oi1, tv0,tv1,tv2,tv3, ti0,ti1,ti2,ti3)
        INS4L(ov2, oi2, tv0,tv1,tv2,tv3, ti0,ti1,ti2,ti3)
        INS4L(ov3, oi3, tv0,tv1,tv2,tv3, ti0,ti1,ti2,ti3)
    }

    if (lane == 0) {
        size_t ob = ((size_t)b*PB + p)*KK;
        idxOut[ob+0]=ti0; idxOut[ob+1]=ti1; idxOut[ob+2]=ti2; idxOut[ob+3]=ti3;
    }
}

// ---------------- logits GEMM: X[24000x64] @ memw^T[64x1024] ----------------
__global__ __launch_bounds__(256) void k_logits(const float* __restrict__ points,
                                                const int* __restrict__ idxIn,
                                                const float* __restrict__ memw,
                                                float* __restrict__ logits,
                                                int b) {
    __shared__ float4 sX4[64*16];
    __shared__ int sId[64];
    const int t = threadIdx.x;
    const int lane = t & 63, wv = t >> 6;
    const int row0 = blockIdx.x * 64;
    const int cg = blockIdx.y * 256 + wv * 64;

    if (t < 64) sId[t] = idxIn[(size_t)b*NROWS + row0 + t];

    const float4* mw4 = (const float4*)memw;
    float4 wreg[16];
    #pragma unroll
    for (int d4 = 0; d4 < 16; d4++) wreg[d4] = mw4[(size_t)(cg + lane)*16 + d4];

    __syncthreads();
    const float4* ptsB4 = (const float4*)(points + (size_t)b*NPTS*DD);
    for (int i = t; i < 1024; i += 256) {
        int r = i >> 4, c = i & 15;
        sX4[i] = ptsB4[(size_t)sId[r]*16 + c];
    }
    __syncthreads();

    for (int r = 0; r < 64; r += 2) {
        float a0 = 0.f, a1 = 0.f;
        #pragma unroll
        for (int d4 = 0; d4 < 16; d4++) {
            float4 x0 = sX4[r*16 + d4];
            float4 x1 = sX4[(r+1)*16 + d4];
            a0 += wreg[d4].x*x0.x + wreg[d4].y*x0.y + wreg[d4].z*x0.z + wreg[d4].w*x0.w;
            a1 += wreg[d4].x*x1.x + wreg[d4].y*x1.y + wreg[d4].z*x1.z + wreg[d4].w*x1.w;
        }
        logits[(size_t)(row0 + r)*MM + cg + lane] = a0;
        logits[(size_t)(row0 + r + 1)*MM + cg + lane] = a1;
    }
}

// ---------------- mem-unit: stats + att-on-the-fly GEMM + adapt ----------------
__global__ __launch_bounds__(256) void k_mo(const float* __restrict__ logits,
                                            const float* __restrict__ memw,
                                            const float* __restrict__ adaptw,
                                            float* __restrict__ hOut,
                                            int b) {
    __shared__ __align__(16) char smem[77824];
    float4* sAtt4 = (float4*)smem;              // [48][16] f4
    float4* sW4   = (float4*)(smem + 12288);    // [64 m][16 c4]
    float*  sWf   = (float*)sW4;
    __shared__ float sM[48], sRinv[48], sRsc[48];
    const int t = threadIdx.x;
    const int lane = t & 63, wv = t >> 6;
    const int p0 = blockIdx.x * 12;
    const int row0 = p0 * 4;

    const float4* lg4 = (const float4*)logits;
    #pragma unroll
    for (int rr = 0; rr < 12; rr++) {
        int r = wv*12 + rr;
        size_t base = (size_t)(row0 + r)*256;
        float4 l0 = lg4[base + lane];
        float4 l1 = lg4[base + 64 + lane];
        float4 l2 = lg4[base + 128 + lane];
        float4 l3 = lg4[base + 192 + lane];
        float m = fmaxf(fmaxf(fmaxf(l0.x,l0.y),fmaxf(l0.z,l0.w)),
                 fmaxf(fmaxf(fmaxf(l1.x,l1.y),fmaxf(l1.z,l1.w)),
                 fmaxf(fmaxf(fmaxf(l2.x,l2.y),fmaxf(l2.z,l2.w)),
                       fmaxf(fmaxf(l3.x,l3.y),fmaxf(l3.z,l3.w)))));
        #pragma unroll
        for (int off = 1; off < 64; off <<= 1) m = fmaxf(m, __shfl_xor(m, off));
        l0.x=__expf(l0.x-m); l0.y=__expf(l0.y-m); l0.z=__expf(l0.z-m); l0.w=__expf(l0.w-m);
        l1.x=__expf(l1.x-m); l1.y=__expf(l1.y-m); l1.z=__expf(l1.z-m); l1.w=__expf(l1.w-m);
        l2.x=__expf(l2.x-m); l2.y=__expf(l2.y-m); l2.z=__expf(l2.z-m); l2.w=__expf(l2.w-m);
        l3.x=__expf(l3.x-m); l3.y=__expf(l3.y-m); l3.z=__expf(l3.z-m); l3.w=__expf(l3.w-m);
        float s = (l0.x+l0.y+l0.z+l0.w) + (l1.x+l1.y+l1.z+l1.w)
                + (l2.x+l2.y+l2.z+l2.w) + (l3.x+l3.y+l3.z+l3.w);
        #pragma unroll
        for (int off = 1; off < 64; off <<= 1) s += __shfl_xor(s, off);
        float rinv = 1.f / s;
        float sh = 0.f;
        {
            float e, tt;
            e=l0.x*rinv; tt=e-SHRINK_TH; sh += tt>0.f ? e*tt/(tt+1e-12f) : 0.f;
            e=l0.y*rinv; tt=e-SHRINK_TH; sh += tt>0.f ? e*tt/(tt+1e-12f) : 0.f;
            e=l0.z*rinv; tt=e-SHRINK_TH; sh += tt>0.f ? e*tt/(tt+1e-12f) : 0.f;
            e=l0.w*rinv; tt=e-SHRINK_TH; sh += tt>0.f ? e*tt/(tt+1e-12f) : 0.f;
            e=l1.x*rinv; tt=e-SHRINK_TH; sh += tt>0.f ? e*tt/(tt+1e-12f) : 0.f;
            e=l1.y*rinv; tt=e-SHRINK_TH; sh += tt>0.f ? e*tt/(tt+1e-12f) : 0.f;
            e=l1.z*rinv; tt=e-SHRINK_TH; sh += tt>0.f ? e*tt/(tt+1e-12f) : 0.f;
            e=l1.w*rinv; tt=e-SHRINK_TH; sh += tt>0.f ? e*tt/(tt+1e-12f) : 0.f;
            e=l2.x*rinv; tt=e-SHRINK_TH; sh += tt>0.f ? e*tt/(tt+1e-12f) : 0.f;
            e=l2.y*rinv; tt=e-SHRINK_TH; sh += tt>0.f ? e*tt/(tt+1e-12f) : 0.f;
            e=l2.z*rinv; tt=e-SHRINK_TH; sh += tt>0.f ? e*tt/(tt+1e-12f) : 0.f;
            e=l2.w*rinv; tt=e-SHRINK_TH; sh += tt>0.f ? e*tt/(tt+1e-12f) : 0.f;
            e=l3.x*rinv; tt=e-SHRINK_TH; sh += tt>0.f ? e*tt/(tt+1e-12f) : 0.f;
            e=l3.y*rinv; tt=e-SHRINK_TH; sh += tt>0.f ? e*tt/(tt+1e-12f) : 0.f;
            e=l3.z*rinv; tt=e-SHRINK_TH; sh += tt>0.f ? e*tt/(tt+1e-12f) : 0.f;
            e=l3.w*rinv; tt=e-SHRINK_TH; sh += tt>0.f ? e*tt/(tt+1e-12f) : 0.f;
        }
        #pragma unroll
        for (int off = 1; off < 64; off <<= 1) sh += __shfl_xor(sh, off);
        if (lane == 0) { sM[r] = m; sRinv[r] = rinv; sRsc[r] = 1.f/(sh + 1e-12f); }
    }
    __syncthreads();

    float acc[12];
    #pragma unroll
    for (int s=0;s<12;s++) acc[s]=0.f;
    const float4* mw4 = (const float4*)memw;

    for (int tile = 0; tile < 16; tile++) {
        __syncthreads();
        for (int i = t; i < 768; i += 256) {
            int rr = i >> 4, m4 = i & 15;
            float4 lg = lg4[(size_t)(row0 + rr)*256 + tile*16 + m4];
            float m = sM[rr], rinv = sRinv[rr], rsc = sRsc[rr];
            float4 o;
            float e, tt;
            e=__expf(lg.x-m)*rinv; tt=e-SHRINK_TH; o.x = (tt>0.f ? e*tt/(tt+1e-12f) : 0.f)*rsc;
            e=__expf(lg.y-m)*rinv; tt=e-SHRINK_TH; o.y = (tt>0.f ? e*tt/(tt+1e-12f) : 0.f)*rsc;
            e=__expf(lg.z-m)*rinv; tt=e-SHRINK_TH; o.z = (tt>0.f ? e*tt/(tt+1e-12f) : 0.f)*rsc;
            e=__expf(lg.w-m)*rinv; tt=e-SHRINK_TH; o.w = (tt>0.f ? e*tt/(tt+1e-12f) : 0.f)*rsc;
            sAtt4[rr*16 + m4] = o;
        }
        #pragma unroll 4
        for (int i = t; i < 1024; i += 256) {
            int m = i >> 4, c4 = i & 15;
            sW4[m*16 + c4] = mw4[(size_t)(tile*64 + m)*16 + c4];
        }
        __syncthreads();
        #pragma unroll 4
        for (int m4 = 0; m4 < 16; m4++) {
            float w0 = sWf[(m4*4+0)*64 + lane];
            float w1 = sWf[(m4*4+1)*64 + lane];
            float w2 = sWf[(m4*4+2)*64 + lane];
            float w3 = sWf[(m4*4+3)*64 + lane];
            #pragma unroll
            for (int s = 0; s < 12; s++) {
                float4 a4 = sAtt4[(wv + 4*s)*16 + m4];
                acc[s] += a4.x*w0 + a4.y*w1 + a4.z*w2 + a4.w*w3;
            }
        }
    }
    __syncthreads();
    float* sMo = (float*)smem;
    float4* sA4 = (float4*)(smem + 12288);
    #pragma unroll
    for (int s = 0; s < 12; s++) {
        int r = wv + 4*s;
        sMo[r*64 + lane] = acc[s];
    }
    const float4* adG4 = (const float4*)adaptw;
    for (int i = t; i < 4096; i += 256) {
        int c = i >> 6, j4 = i & 63;
        sA4[c*64 + (j4 ^ (c & 15))] = adG4[c*64 + j4];
    }
    __syncthreads();
    const float4* sMo4 = (const float4*)sMo;
    float h0=0.f, h1=0.f, h2=0.f;
    #pragma unroll 8
    for (int j4 = 0; j4 < 64; j4++) {
        float4 a4 = sA4[lane*64 + (j4 ^ (lane & 15))];
        int sub = (j4 >> 4)*16 + (j4 & 15);
        float4 q0 = sMo4[(4*(wv+0))*16 + sub];
        float4 q1 = sMo4[(4*(wv+4))*16 + sub];
        float4 q2 = sMo4[(4*(wv+8))*16 + sub];
        h0 += q0.x*a4.x + q0.y*a4.y + q0.z*a4.z + q0.w*a4.w;
        h1 += q1.x*a4.x + q1.y*a4.y + q1.z*a4.z + q1.w*a4.w;
        h2 += q2.x*a4.x + q2.y*a4.y + q2.z*a4.z + q2.w*a4.w;
    }
    hOut[((size_t)b*PB + p0 + wv + 0)*DD + lane] = h0;
    hOut[((size_t)b*PB + p0 + wv + 4)*DD + lane] = h1;
    hOut[((size_t)b*PB + p0 + wv + 8)*DD + lane] = h2;
}

// ---------------- batchnorm stats, two-stage ----------------
__global__ __launch_bounds__(256) void k_bn1(const float* __restrict__ h,
                                             float* __restrict__ pSum,
                                             float* __restrict__ pSq) {
    const int bid = blockIdx.x;
    const int b = bid >> 5, ch = bid & 31;
    const int r0 = ch*188;
    int r1 = r0 + 188; if (r1 > PB) r1 = PB;
    __shared__ float sS[4*64], sS2[4*64];
    const int t = threadIdx.x;
    const int c = t & 63, stripe = t >> 6;
    float s = 0.f, s2 = 0.f;
    for (int r = r0 + stripe; r < r1; r += 4) {
        float v = h[((size_t)b*PB + r)*DD + c];
        s += v; s2 += v*v;
    }
    sS[stripe*64 + c] = s; sS2[stripe*64 + c] = s2;
    __syncthreads();
    if (t < 64) {
        float ts = sS[t] + sS[64+t] + sS[128+t] + sS[192+t];
        float ts2 = sS2[t] + sS2[64+t] + sS2[128+t] + sS2[192+t];
        pSum[(size_t)bid*64 + t] = ts;
        pSq[(size_t)bid*64 + t] = ts2;
    }
}

__global__ __launch_bounds__(64) void k_bn2(const float* __restrict__ pSum,
                                            const float* __restrict__ pSq,
                                            const float* __restrict__ gamma,
                                            float* __restrict__ bnMu,
                                            float* __restrict__ bnScale) {
    const int b = blockIdx.x;
    const int t = threadIdx.x;
    float ts = 0.f, ts2 = 0.f;
    for (int ch = 0; ch < 32; ch++) {
        ts += pSum[(size_t)(b*32 + ch)*64 + t];
        ts2 += pSq[(size_t)(b*32 + ch)*64 + t];
    }
    float mu = ts / (float)PB;
    float var = ts2 / (float)PB - mu*mu;
    if (var < 0.f) var = 0.f;
    bnMu[b*64+t] = mu;
    bnScale[b*64+t] = gamma[t] / sqrtf(var + BN_EPS);
}

// ---------------- dense fill (gather) ----------------
__global__ __launch_bounds__(256) void k_fill(const int* __restrict__ inv,
                                              const float* __restrict__ pillars,
                                              const float* __restrict__ h,
                                              const float* __restrict__ bnMu,
                                              const float* __restrict__ bnScale,
                                              const float* __restrict__ beta,
                                              float* __restrict__ out) {
    const int b = blockIdx.y;
    const int f = blockIdx.x*256 + threadIdx.x;
    __shared__ float sMu[64], sSc[64], sBe[64];
    if (threadIdx.x < 64) {
        sMu[threadIdx.x] = bnMu[b*64+threadIdx.x];
        sSc[threadIdx.x] = bnScale[b*64+threadIdx.x];
        sBe[threadIdx.x] = beta[threadIdx.x];
    }
    __syncthreads();
    int iv = inv[b*SCELLS + f];
    bool occ = iv >= 0;
    int iv0 = occ ? iv : 0;
    float* sp = out + (size_t)b*128*SCELLS;
    const float* prow = pillars + ((size_t)b*PB + iv0)*DD;
    const float* hrow = h + ((size_t)b*PB + iv0)*DD;
    #pragma unroll 4
    for (int c = 0; c < 64; c++)
        sp[(size_t)c*SCELLS + f] = occ ? prow[c] : 0.f;
    #pragma unroll 4
    for (int c = 0; c < 64; c++) {
        float v = 0.f;
        if (occ) {
            float hv = hrow[c];
            v = fmaxf((hv - sMu[c])*sSc[c] + sBe[c], 0.f);
        }
        sp[(size_t)(64+c)*SCELLS + f] = v;
    }
    float* pi = out + (size_t)BB*128*SCELLS + (size_t)b*3*SCELLS;
    pi[f]              = occ ? (float)(f / NXg) : 0.f;
    pi[SCELLS + f]     = occ ? (float)(f % NXg) : 0.f;
    pi[2*(size_t)SCELLS + f] = 0.f;
}

extern "C" void kernel_launch(void* const* d_in, const int* in_sizes, int n_in,
                              void* d_out, int out_size, void* d_ws, size_t ws_size,
                              hipStream_t stream) {
    const float* pillars = (const float*)d_in[0];
    const float* points  = (const float*)d_in[1];
    const int*   coords  = (const int*)d_in[2];
    const float* adaptw  = (const float*)d_in[3];
    const float* memw    = (const float*)d_in[4];
    const float* gamma   = (const float*)d_in[5];
    const float* beta    = (const float*)d_in[6];
    float* out = (float*)d_out;

    char* w = (char*)d_ws;
    int* inv = (int*)w;        w += (size_t)BB*SCELLS*4;
    int* idx = (int*)w;        w += (size_t)BB*PB*KK*4;
    float* h = (float*)w;      w += (size_t)BB*PB*DD*4;
    float* bnMu = (float*)w;   w += (size_t)BB*64*4;
    float* bnScale = (float*)w; w += (size_t)BB*64*4;
    float* pSum = (float*)w;   w += (size_t)BB*32*64*4;
    float* pSq = (float*)w;    w += (size_t)BB*32*64*4;
    float* logits = (float*)w;                    // 98.3 MB, per-batch reuse
    // scores aliases logits: PB*NPTS floats == NROWS*MM floats (both 24.576M).
    // Sequencing (stream-ordered): score(0),scan(0),score(1),scan(1) all
    // complete before k_logits(0) overwrites the region; idx extracted first.
    float* scores = logits;

    k_init_inv<<<dim3(BB*SCELLS/256), dim3(256), 0, stream>>>(inv);
    k_scatter_inv<<<dim3((BB*PB+255)/256), dim3(256), 0, stream>>>(coords, inv);
    for (int b = 0; b < BB; b++) {
        k_score<<<dim3(NPBLK, NYBLK), dim3(256), 0, stream>>>(pillars, points, scores, b);
        k_scan<<<dim3(PB/4), dim3(256), 0, stream>>>(scores, idx, b);
    }
    for (int b = 0; b < BB; b++) {
        k_logits<<<dim3(NROWS/64, 4), dim3(256), 0, stream>>>(points, idx, memw, logits, b);
        k_mo<<<dim3(PB/12), dim3(256), 0, stream>>>(logits, memw, adaptw, h, b);
    }
    k_bn1<<<dim3(BB*32), dim3(256), 0, stream>>>(h, pSum, pSq);
    k_bn2<<<dim3(BB), dim3(64), 0, stream>>>(pSum, pSq, gamma, bnMu, bnScale);
    k_fill<<<dim3(SCELLS/256, BB), dim3(256), 0, stream>>>(inv, pillars, h, bnMu, bnScale, beta, out);
}

// Round 7
// 761.056 us; speedup vs baseline: 6.1165x; 4.2071x over previous
//
#include <hip/hip_runtime.h>

#define NXg 432
#define NYg 496
#define SCELLS (NXg*NYg)   // 214272
#define PB 6000
#define NPTS 4096
#define DD 64
#define MM 1024
#define KK 4
#define BB 2
#define NROWS (PB*KK)      // 24000
#define NSEG 16
#define SEGPTS (NPTS/NSEG) // 256 points per segment
#define CHROWS 64          // point rows staged per LDS chunk
#define NCHNK (SEGPTS/CHROWS) // 4 chunks
#define SHRINK_TH 0.0025f
#define BN_EPS 1e-3f
#define NEG_INF -3.402823466e38f

// sorted-descending top-4 insert on NAMED scalars; caller guarantees v > v3.
// Scans are ascending-index, so strict > keeps earliest index on ties.
#define INS4(v, id, v0,v1,v2,v3, i0,i1,i2,i3) { \
    bool g0 = (v) > v0, g1 = (v) > v1, g2 = (v) > v2; \
    v3 = g2 ? v2 : (v);              i3 = g2 ? i2 : (id); \
    v2 = g2 ? (g1 ? v1 : (v)) : v2;  i2 = g2 ? (g1 ? i1 : (id)) : i2; \
    v1 = g1 ? (g0 ? v0 : (v)) : v1;  i1 = g1 ? (g0 ? i0 : (id)) : i1; \
    v0 = g0 ? (v) : v0;              i0 = g0 ? (id) : i0; \
}

// ---------------- inverse map ----------------
__global__ __launch_bounds__(256) void k_init_inv(int* __restrict__ inv) {
    int i = blockIdx.x*256 + threadIdx.x;
    inv[i] = -1;
}

__global__ __launch_bounds__(256) void k_scatter_inv(const int* __restrict__ coords,
                                                     int* __restrict__ inv) {
    int i = blockIdx.x*256 + threadIdx.x;
    if (i >= BB*PB) return;
    int b = i / PB, p = i % PB;
    const int* c = coords + (size_t)i*3;
    int flat = c[0] + c[1]*NXg + c[2];
    inv[b*SCELLS + flat] = p;
}

// ---------------- score + top-4: k_logits-pattern, fused ----------------
// Rounds 4-6 post-mortem: every structure whose LDS reads used lane-computed
// (XOR-swizzled) addresses spilled (VGPR 84/84/256, GB-scale scratch traffic):
// hoisted unrolled reads keep addresses AND data live. k_logits -- the one
// GEMM here that never spills -- reads LDS at base + compile-time immediate
// offsets, broadcast across lanes. This kernel is its clone, transposed:
//   - thread owns one PILLAR row in wreg[16] (k_logits's weight pattern)
//   - 64 POINT rows staged per chunk in plain LDS (no swizzle needed:
//     reads are same-address broadcasts -> conflict-free by definition)
//   - inner loop = k_logits's exact body (2 dot products per iter,
//     immediate-offset ds_read), but the 2 scalars feed INS4 (8 topk regs)
//     instead of global stores. No scores matrix, no scan kernel.
// grid (24, BB, NSEG=16): 768 blocks ~ 3/CU; LDS 16KB; regs ~95 -> no spill.
__global__ __launch_bounds__(256) void k_score_topk(const float* __restrict__ pillars,
                                                    const float* __restrict__ points,
                                                    float* __restrict__ pV,
                                                    int* __restrict__ pI) {
    __shared__ float4 sPt[CHROWS*16];     // 64 point rows, 16 KB
    const int b = blockIdx.y;
    const int seg = blockIdx.z;
    const int t = threadIdx.x;
    const int pillar = blockIdx.x*256 + t;
    const int prow = pillar < PB ? pillar : PB-1;
    const int j0 = seg * SEGPTS;

    const float4* pil4  = (const float4*)pillars;
    const float4* ptsB4 = (const float4*)(points + (size_t)b*NPTS*DD);

    float4 wreg[16];
    #pragma unroll
    for (int d4 = 0; d4 < 16; d4++)
        wreg[d4] = pil4[((size_t)b*PB + prow)*16 + d4];

    float tv0=NEG_INF, tv1=NEG_INF, tv2=NEG_INF, tv3=NEG_INF;
    int   ti0=0, ti1=0, ti2=0, ti3=0;

    for (int ch = 0; ch < NCHNK; ch++) {
        // stage 64 point rows (coalesced; rows consecutive so base+i works)
        const float4* src = ptsB4 + (size_t)(j0 + ch*CHROWS)*16;
        for (int i = t; i < CHROWS*16; i += 256)
            sPt[i] = src[i];
        __syncthreads();

        const int jb = j0 + ch*CHROWS;
        for (int j = 0; j < CHROWS; j += 2) {
            float a0 = 0.f, a1 = 0.f;
            #pragma unroll
            for (int d4 = 0; d4 < 16; d4++) {
                float4 x0 = sPt[j*16 + d4];
                float4 x1 = sPt[(j+1)*16 + d4];
                a0 += wreg[d4].x*x0.x + wreg[d4].y*x0.y + wreg[d4].z*x0.z + wreg[d4].w*x0.w;
                a1 += wreg[d4].x*x1.x + wreg[d4].y*x1.y + wreg[d4].z*x1.z + wreg[d4].w*x1.w;
            }
            if (a0 > tv3) INS4(a0, jb+j,   tv0,tv1,tv2,tv3, ti0,ti1,ti2,ti3)
            if (a1 > tv3) INS4(a1, jb+j+1, tv0,tv1,tv2,tv3, ti0,ti1,ti2,ti3)
        }
        __syncthreads();   // all reads done before next chunk overwrites sPt
    }

    if (pillar < PB) {
        size_t ob = (((size_t)b*NSEG + seg)*PB + pillar)*KK;
        pV[ob+0]=tv0; pV[ob+1]=tv1; pV[ob+2]=tv2; pV[ob+3]=tv3;
        pI[ob+0]=ti0; pI[ob+1]=ti1; pI[ob+2]=ti2; pI[ob+3]=ti3;
    }
}

// ---------------- merge NSEG partial top-4 lists ----------------
__global__ __launch_bounds__(256) void k_merge(const float* __restrict__ pV,
                                               const int* __restrict__ pI,
                                               int* __restrict__ idxOut) {
    int i = blockIdx.x*256 + threadIdx.x;
    if (i >= BB*PB) return;
    int b = i / PB, p = i % PB;
    float fv0=NEG_INF, fv1=NEG_INF, fv2=NEG_INF, fv3=NEG_INF;
    int fi0=0, fi1=0, fi2=0, fi3=0;
    for (int s = 0; s < NSEG; s++) {   // ascending seg = ascending point ranges
        size_t base = (((size_t)b*NSEG + s)*PB + p)*KK;
        #pragma unroll
        for (int q = 0; q < 4; q++) {
            float v = pV[base+q];
            if (v > fv3) INS4(v, pI[base+q], fv0,fv1,fv2,fv3, fi0,fi1,fi2,fi3)
        }
    }
    idxOut[(size_t)i*KK+0]=fi0; idxOut[(size_t)i*KK+1]=fi1;
    idxOut[(size_t)i*KK+2]=fi2; idxOut[(size_t)i*KK+3]=fi3;
}

// ---------------- logits GEMM: X[24000x64] @ memw^T[64x1024] ----------------
__global__ __launch_bounds__(256) void k_logits(const float* __restrict__ points,
                                                const int* __restrict__ idxIn,
                                                const float* __restrict__ memw,
                                                float* __restrict__ logits,
                                                int b) {
    __shared__ float4 sX4[64*16];
    __shared__ int sId[64];
    const int t = threadIdx.x;
    const int lane = t & 63, wv = t >> 6;
    const int row0 = blockIdx.x * 64;
    const int cg = blockIdx.y * 256 + wv * 64;

    if (t < 64) sId[t] = idxIn[(size_t)b*NROWS + row0 + t];

    const float4* mw4 = (const float4*)memw;
    float4 wreg[16];
    #pragma unroll
    for (int d4 = 0; d4 < 16; d4++) wreg[d4] = mw4[(size_t)(cg + lane)*16 + d4];

    __syncthreads();
    const float4* ptsB4 = (const float4*)(points + (size_t)b*NPTS*DD);
    for (int i = t; i < 1024; i += 256) {
        int r = i >> 4, c = i & 15;
        sX4[i] = ptsB4[(size_t)sId[r]*16 + c];
    }
    __syncthreads();

    for (int r = 0; r < 64; r += 2) {
        float a0 = 0.f, a1 = 0.f;
        #pragma unroll
        for (int d4 = 0; d4 < 16; d4++) {
            float4 x0 = sX4[r*16 + d4];
            float4 x1 = sX4[(r+1)*16 + d4];
            a0 += wreg[d4].x*x0.x + wreg[d4].y*x0.y + wreg[d4].z*x0.z + wreg[d4].w*x0.w;
            a1 += wreg[d4].x*x1.x + wreg[d4].y*x1.y + wreg[d4].z*x1.z + wreg[d4].w*x1.w;
        }
        logits[(size_t)(row0 + r)*MM + cg + lane] = a0;
        logits[(size_t)(row0 + r + 1)*MM + cg + lane] = a1;
    }
}

// ---------------- mem-unit: stats + att-on-the-fly GEMM + adapt ----------------
__global__ __launch_bounds__(256) void k_mo(const float* __restrict__ logits,
                                            const float* __restrict__ memw,
                                            const float* __restrict__ adaptw,
                                            float* __restrict__ hOut,
                                            int b) {
    __shared__ __align__(16) char smem[77824];
    float4* sAtt4 = (float4*)smem;              // [48][16] f4
    float4* sW4   = (float4*)(smem + 12288);    // [64 m][16 c4]
    float*  sWf   = (float*)sW4;
    __shared__ float sM[48], sRinv[48], sRsc[48];
    const int t = threadIdx.x;
    const int lane = t & 63, wv = t >> 6;
    const int p0 = blockIdx.x * 12;
    const int row0 = p0 * 4;

    const float4* lg4 = (const float4*)logits;
    #pragma unroll
    for (int rr = 0; rr < 12; rr++) {
        int r = wv*12 + rr;
        size_t base = (size_t)(row0 + r)*256;
        float4 l0 = lg4[base + lane];
        float4 l1 = lg4[base + 64 + lane];
        float4 l2 = lg4[base + 128 + lane];
        float4 l3 = lg4[base + 192 + lane];
        float m = fmaxf(fmaxf(fmaxf(l0.x,l0.y),fmaxf(l0.z,l0.w)),
                 fmaxf(fmaxf(fmaxf(l1.x,l1.y),fmaxf(l1.z,l1.w)),
                 fmaxf(fmaxf(fmaxf(l2.x,l2.y),fmaxf(l2.z,l2.w)),
                       fmaxf(fmaxf(l3.x,l3.y),fmaxf(l3.z,l3.w)))));
        #pragma unroll
        for (int off = 1; off < 64; off <<= 1) m = fmaxf(m, __shfl_xor(m, off));
        l0.x=__expf(l0.x-m); l0.y=__expf(l0.y-m); l0.z=__expf(l0.z-m); l0.w=__expf(l0.w-m);
        l1.x=__expf(l1.x-m); l1.y=__expf(l1.y-m); l1.z=__expf(l1.z-m); l1.w=__expf(l1.w-m);
        l2.x=__expf(l2.x-m); l2.y=__expf(l2.y-m); l2.z=__expf(l2.z-m); l2.w=__expf(l2.w-m);
        l3.x=__expf(l3.x-m); l3.y=__expf(l3.y-m); l3.z=__expf(l3.z-m); l3.w=__expf(l3.w-m);
        float s = (l0.x+l0.y+l0.z+l0.w) + (l1.x+l1.y+l1.z+l1.w)
                + (l2.x+l2.y+l2.z+l2.w) + (l3.x+l3.y+l3.z+l3.w);
        #pragma unroll
        for (int off = 1; off < 64; off <<= 1) s += __shfl_xor(s, off);
        float rinv = 1.f / s;
        float sh = 0.f;
        {
            float e, tt;
            e=l0.x*rinv; tt=e-SHRINK_TH; sh += tt>0.f ? e*tt/(tt+1e-12f) : 0.f;
            e=l0.y*rinv; tt=e-SHRINK_TH; sh += tt>0.f ? e*tt/(tt+1e-12f) : 0.f;
            e=l0.z*rinv; tt=e-SHRINK_TH; sh += tt>0.f ? e*tt/(tt+1e-12f) : 0.f;
            e=l0.w*rinv; tt=e-SHRINK_TH; sh += tt>0.f ? e*tt/(tt+1e-12f) : 0.f;
            e=l1.x*rinv; tt=e-SHRINK_TH; sh += tt>0.f ? e*tt/(tt+1e-12f) : 0.f;
            e=l1.y*rinv; tt=e-SHRINK_TH; sh += tt>0.f ? e*tt/(tt+1e-12f) : 0.f;
            e=l1.z*rinv; tt=e-SHRINK_TH; sh += tt>0.f ? e*tt/(tt+1e-12f) : 0.f;
            e=l1.w*rinv; tt=e-SHRINK_TH; sh += tt>0.f ? e*tt/(tt+1e-12f) : 0.f;
            e=l2.x*rinv; tt=e-SHRINK_TH; sh += tt>0.f ? e*tt/(tt+1e-12f) : 0.f;
            e=l2.y*rinv; tt=e-SHRINK_TH; sh += tt>0.f ? e*tt/(tt+1e-12f) : 0.f;
            e=l2.z*rinv; tt=e-SHRINK_TH; sh += tt>0.f ? e*tt/(tt+1e-12f) : 0.f;
            e=l2.w*rinv; tt=e-SHRINK_TH; sh += tt>0.f ? e*tt/(tt+1e-12f) : 0.f;
            e=l3.x*rinv; tt=e-SHRINK_TH; sh += tt>0.f ? e*tt/(tt+1e-12f) : 0.f;
            e=l3.y*rinv; tt=e-SHRINK_TH; sh += tt>0.f ? e*tt/(tt+1e-12f) : 0.f;
            e=l3.z*rinv; tt=e-SHRINK_TH; sh += tt>0.f ? e*tt/(tt+1e-12f) : 0.f;
            e=l3.w*rinv; tt=e-SHRINK_TH; sh += tt>0.f ? e*tt/(tt+1e-12f) : 0.f;
        }
        #pragma unroll
        for (int off = 1; off < 64; off <<= 1) sh += __shfl_xor(sh, off);
        if (lane == 0) { sM[r] = m; sRinv[r] = rinv; sRsc[r] = 1.f/(sh + 1e-12f); }
    }
    __syncthreads();

    float acc[12];
    #pragma unroll
    for (int s=0;s<12;s++) acc[s]=0.f;
    const float4* mw4 = (const float4*)memw;

    for (int tile = 0; tile < 16; tile++) {
        __syncthreads();
        for (int i = t; i < 768; i += 256) {
            int rr = i >> 4, m4 = i & 15;
            float4 lg = lg4[(size_t)(row0 + rr)*256 + tile*16 + m4];
            float m = sM[rr], rinv = sRinv[rr], rsc = sRsc[rr];
            float4 o;
            float e, tt;
            e=__expf(lg.x-m)*rinv; tt=e-SHRINK_TH; o.x = (tt>0.f ? e*tt/(tt+1e-12f) : 0.f)*rsc;
            e=__expf(lg.y-m)*rinv; tt=e-SHRINK_TH; o.y = (tt>0.f ? e*tt/(tt+1e-12f) : 0.f)*rsc;
            e=__expf(lg.z-m)*rinv; tt=e-SHRINK_TH; o.z = (tt>0.f ? e*tt/(tt+1e-12f) : 0.f)*rsc;
            e=__expf(lg.w-m)*rinv; tt=e-SHRINK_TH; o.w = (tt>0.f ? e*tt/(tt+1e-12f) : 0.f)*rsc;
            sAtt4[rr*16 + m4] = o;
        }
        #pragma unroll 4
        for (int i = t; i < 1024; i += 256) {
            int m = i >> 4, c4 = i & 15;
            sW4[m*16 + c4] = mw4[(size_t)(tile*64 + m)*16 + c4];
        }
        __syncthreads();
        #pragma unroll 4
        for (int m4 = 0; m4 < 16; m4++) {
            float w0 = sWf[(m4*4+0)*64 + lane];
            float w1 = sWf[(m4*4+1)*64 + lane];
            float w2 = sWf[(m4*4+2)*64 + lane];
            float w3 = sWf[(m4*4+3)*64 + lane];
            #pragma unroll
            for (int s = 0; s < 12; s++) {
                float4 a4 = sAtt4[(wv + 4*s)*16 + m4];
                acc[s] += a4.x*w0 + a4.y*w1 + a4.z*w2 + a4.w*w3;
            }
        }
    }
    __syncthreads();
    float* sMo = (float*)smem;
    float4* sA4 = (float4*)(smem + 12288);
    #pragma unroll
    for (int s = 0; s < 12; s++) {
        int r = wv + 4*s;
        sMo[r*64 + lane] = acc[s];
    }
    const float4* adG4 = (const float4*)adaptw;
    for (int i = t; i < 4096; i += 256) {
        int c = i >> 6, j4 = i & 63;
        sA4[c*64 + (j4 ^ (c & 15))] = adG4[c*64 + j4];
    }
    __syncthreads();
    const float4* sMo4 = (const float4*)sMo;
    float h0=0.f, h1=0.f, h2=0.f;
    #pragma unroll 8
    for (int j4 = 0; j4 < 64; j4++) {
        float4 a4 = sA4[lane*64 + (j4 ^ (lane & 15))];
        int sub = (j4 >> 4)*16 + (j4 & 15);
        float4 q0 = sMo4[(4*(wv+0))*16 + sub];
        float4 q1 = sMo4[(4*(wv+4))*16 + sub];
        float4 q2 = sMo4[(4*(wv+8))*16 + sub];
        h0 += q0.x*a4.x + q0.y*a4.y + q0.z*a4.z + q0.w*a4.w;
        h1 += q1.x*a4.x + q1.y*a4.y + q1.z*a4.z + q1.w*a4.w;
        h2 += q2.x*a4.x + q2.y*a4.y + q2.z*a4.z + q2.w*a4.w;
    }
    hOut[((size_t)b*PB + p0 + wv + 0)*DD + lane] = h0;
    hOut[((size_t)b*PB + p0 + wv + 4)*DD + lane] = h1;
    hOut[((size_t)b*PB + p0 + wv + 8)*DD + lane] = h2;
}

// ---------------- batchnorm stats, two-stage ----------------
__global__ __launch_bounds__(256) void k_bn1(const float* __restrict__ h,
                                             float* __restrict__ pSum,
                                             float* __restrict__ pSq) {
    const int bid = blockIdx.x;
    const int b = bid >> 5, ch = bid & 31;
    const int r0 = ch*188;
    int r1 = r0 + 188; if (r1 > PB) r1 = PB;
    __shared__ float sS[4*64], sS2[4*64];
    const int t = threadIdx.x;
    const int c = t & 63, stripe = t >> 6;
    float s = 0.f, s2 = 0.f;
    for (int r = r0 + stripe; r < r1; r += 4) {
        float v = h[((size_t)b*PB + r)*DD + c];
        s += v; s2 += v*v;
    }
    sS[stripe*64 + c] = s; sS2[stripe*64 + c] = s2;
    __syncthreads();
    if (t < 64) {
        float ts = sS[t] + sS[64+t] + sS[128+t] + sS[192+t];
        float ts2 = sS2[t] + sS2[64+t] + sS2[128+t] + sS2[192+t];
        pSum[(size_t)bid*64 + t] = ts;
        pSq[(size_t)bid*64 + t] = ts2;
    }
}

__global__ __launch_bounds__(64) void k_bn2(const float* __restrict__ pSum,
                                            const float* __restrict__ pSq,
                                            const float* __restrict__ gamma,
                                            float* __restrict__ bnMu,
                                            float* __restrict__ bnScale) {
    const int b = blockIdx.x;
    const int t = threadIdx.x;
    float ts = 0.f, ts2 = 0.f;
    for (int ch = 0; ch < 32; ch++) {
        ts += pSum[(size_t)(b*32 + ch)*64 + t];
        ts2 += pSq[(size_t)(b*32 + ch)*64 + t];
    }
    float mu = ts / (float)PB;
    float var = ts2 / (float)PB - mu*mu;
    if (var < 0.f) var = 0.f;
    bnMu[b*64+t] = mu;
    bnScale[b*64+t] = gamma[t] / sqrtf(var + BN_EPS);
}

// ---------------- dense fill (gather) ----------------
__global__ __launch_bounds__(256) void k_fill(const int* __restrict__ inv,
                                              const float* __restrict__ pillars,
                                              const float* __restrict__ h,
                                              const float* __restrict__ bnMu,
                                              const float* __restrict__ bnScale,
                                              const float* __restrict__ beta,
                                              float* __restrict__ out) {
    const int b = blockIdx.y;
    const int f = blockIdx.x*256 + threadIdx.x;
    __shared__ float sMu[64], sSc[64], sBe[64];
    if (threadIdx.x < 64) {
        sMu[threadIdx.x] = bnMu[b*64+threadIdx.x];
        sSc[threadIdx.x] = bnScale[b*64+threadIdx.x];
        sBe[threadIdx.x] = beta[threadIdx.x];
    }
    __syncthreads();
    int iv = inv[b*SCELLS + f];
    bool occ = iv >= 0;
    int iv0 = occ ? iv : 0;
    float* sp = out + (size_t)b*128*SCELLS;
    const float* prow = pillars + ((size_t)b*PB + iv0)*DD;
    const float* hrow = h + ((size_t)b*PB + iv0)*DD;
    #pragma unroll 4
    for (int c = 0; c < 64; c++)
        sp[(size_t)c*SCELLS + f] = occ ? prow[c] : 0.f;
    #pragma unroll 4
    for (int c = 0; c < 64; c++) {
        float v = 0.f;
        if (occ) {
            float hv = hrow[c];
            v = fmaxf((hv - sMu[c])*sSc[c] + sBe[c], 0.f);
        }
        sp[(size_t)(64+c)*SCELLS + f] = v;
    }
    float* pi = out + (size_t)BB*128*SCELLS + (size_t)b*3*SCELLS;
    pi[f]              = occ ? (float)(f / NXg) : 0.f;
    pi[SCELLS + f]     = occ ? (float)(f % NXg) : 0.f;
    pi[2*(size_t)SCELLS + f] = 0.f;
}

extern "C" void kernel_launch(void* const* d_in, const int* in_sizes, int n_in,
                              void* d_out, int out_size, void* d_ws, size_t ws_size,
                              hipStream_t stream) {
    const float* pillars = (const float*)d_in[0];
    const float* points  = (const float*)d_in[1];
    const int*   coords  = (const int*)d_in[2];
    const float* adaptw  = (const float*)d_in[3];
    const float* memw    = (const float*)d_in[4];
    const float* gamma   = (const float*)d_in[5];
    const float* beta    = (const float*)d_in[6];
    float* out = (float*)d_out;

    char* w = (char*)d_ws;
    int* inv = (int*)w;        w += (size_t)BB*SCELLS*4;
    int* idx = (int*)w;        w += (size_t)BB*PB*KK*4;
    float* h = (float*)w;      w += (size_t)BB*PB*DD*4;
    float* bnMu = (float*)w;   w += (size_t)BB*64*4;
    float* bnScale = (float*)w; w += (size_t)BB*64*4;
    float* pSum = (float*)w;   w += (size_t)BB*32*64*4;
    float* pSq = (float*)w;    w += (size_t)BB*32*64*4;
    float* logits = (float*)w;                    // 98.3 MB, per-batch reuse
    // pV/pI alias logits: score+merge fully complete (stream-ordered) before
    // k_logits writes this region. 2*16*6000*4*4B*2 = 6.1 MB << 98.3 MB.
    float* pV = logits;
    int*   pI = (int*)(logits + (size_t)BB*NSEG*PB*KK);

    k_init_inv<<<dim3(BB*SCELLS/256), dim3(256), 0, stream>>>(inv);
    k_scatter_inv<<<dim3((BB*PB+255)/256), dim3(256), 0, stream>>>(coords, inv);
    k_score_topk<<<dim3((PB+255)/256, BB, NSEG), dim3(256), 0, stream>>>(pillars, points, pV, pI);
    k_merge<<<dim3((BB*PB+255)/256), dim3(256), 0, stream>>>(pV, pI, idx);
    for (int b = 0; b < BB; b++) {
        k_logits<<<dim3(NROWS/64, 4), dim3(256), 0, stream>>>(points, idx, memw, logits, b);
        k_mo<<<dim3(PB/12), dim3(256), 0, stream>>>(logits, memw, adaptw, h, b);
    }
    k_bn1<<<dim3(BB*32), dim3(256), 0, stream>>>(h, pSum, pSq);
    k_bn2<<<dim3(BB), dim3(64), 0, stream>>>(pSum, pSq, gamma, bnMu, bnScale);
    k_fill<<<dim3(SCELLS/256, BB), dim3(256), 0, stream>>>(inv, pillars, h, bnMu, bnScale, beta, out);
}